// Round 8
// baseline (518.758 us; speedup 1.0000x reference)
//
#include <hip/hip_runtime.h>
#include <hip/hip_fp16.h>

#define N_NODES 500000
typedef unsigned int u32;
typedef unsigned short u16;

// ===========================================================================
// R17 = R16 + sc1 (L2-bypass) on the rec stream loads.
// R16 post-mortem: layer time invariant to footprint/payload/ILP/occupancy.
// Model: gathers miss L2 (the 64MB rec stream evicts everything) -> every
// gather moves a 64B line from L3: 16M x 64B = 1GB/pass = 5.8 TB/s = L3
// line-BW saturation. Fix: rec loads via global_load_dwordx4 sc1 nt -> on
// gfx950 sc1 loads are device-coherent and BYPASS the per-XCD L2, so the
// fp16 gather arrays (m1h 1MB + h2mh 2MB) stay L2-resident; gathers become
// L2 hits and the L3 wall evaporates.
//   rec = dl9<<19 | src19   per 512-node dst bucket.
// ===========================================================================
#define NPB    512
#define NBUCK  ((N_NODES + NPB - 1) / NPB)   // 977
#define CAP    20480          // region capacity; E[fill]=16384, sigma~128 (32σ)
#define CH     8192           // edges per scatter chunk/WG
#define EPT    8              // edges per thread in scatter (CH / 1024)
#define STB    1024           // scatter block
#define LTB    512            // layer/deg block
#define SRC19  0x7FFFFu

typedef unsigned int v4u __attribute__((ext_vector_type(4)));
__device__ inline int  nt1i(const int* p) { return __builtin_nontemporal_load(p); }
__device__ inline u32  nt1u(const u32* p) { return __builtin_nontemporal_load(p); }
__device__ inline v4u  nt4u(const u32* p) { return __builtin_nontemporal_load((const v4u*)p); }

// rec stream load: sc1 -> bypasses the per-XCD L2 (device-coherent path),
// nt -> no-reuse hint. Embedded waitcnt(0): the compiler can't track an
// inline-asm load's vmcnt; wave-level overlap (4-5 waves/SIMD) hides it.
__device__ inline v4u stream4(const u32* p) {
    v4u r;
    asm volatile("global_load_dwordx4 %0, %1, off sc1 nt\n\t"
                 "s_waitcnt vmcnt(0)"
                 : "=v"(r) : "v"(p));
    return r;
}

// fp16 helpers (storage = u16 / u32-packed half2; math in f32)
__device__ inline float ldh(const u16* p) {
    __half h = *(const __half*)p;
    return __half2float(h);
}
__device__ inline u16 sth(float v) {
    __half h = __float2half(v);
    return *(u16*)&h;
}
__device__ inline u32 pack2h(float a, float b) {
    union { __half2 h; u32 u; } cvt;
    cvt.h = __floats2half2_rn(a, b);
    return cvt.u;
}
__device__ inline float2 unpack2h(u32 w) {
    union { u32 u; __half2 h; } cvt;
    cvt.u = w;
    return __half22float2(cvt.h);
}

// ---- fused scatter: edges register-cached; LDS histogram + scan + presort;
//      coalesced run writes into fixed bucket regions.  (R9 verbatim)
__global__ __launch_bounds__(STB) void k_scatter_fused(
        const int* __restrict__ src, const int* __restrict__ dst, int E,
        u32* __restrict__ cur_g, u32* __restrict__ rec) {
    __shared__ u32 srec[CH];        // 32 KB
    __shared__ u16 sbk[CH];         // 16 KB
    __shared__ u32 hist[NBUCK];     // 3.9 KB
    __shared__ u32 sc[1024];        // 4 KB
    __shared__ u32 scn_ex[NBUCK];
    __shared__ u32 cur2[NBUCK];
    __shared__ u32 gbase[NBUCK];
    int tid = threadIdx.x, bid = blockIdx.x;
    for (int b = tid; b < NBUCK; b += STB) hist[b] = 0;
    __syncthreads();
    int e0 = bid * CH, e1 = min(E, e0 + CH), n = e1 - e0;
    u32 dv[EPT], sv[EPT];
#pragma unroll
    for (int k = 0; k < EPT; ++k) {
        int e = e0 + (k << 10) + tid;
        if (e < e1) {
            dv[k] = (u32)nt1i(dst + e);
            sv[k] = (u32)nt1i(src + e);
            atomicAdd(&hist[dv[k] >> 9], 1u);
        }
    }
    __syncthreads();
    sc[tid] = (tid < NBUCK) ? hist[tid] : 0u;
    __syncthreads();
    for (int off = 1; off < 1024; off <<= 1) {
        u32 t = (tid >= off) ? sc[tid - off] : 0u;
        __syncthreads();
        sc[tid] += t;
        __syncthreads();
    }
    if (tid < NBUCK) {
        u32 ex = sc[tid] - hist[tid];
        scn_ex[tid] = ex;
        cur2[tid] = ex;
        gbase[tid] = hist[tid] ? atomicAdd(&cur_g[tid], hist[tid]) : 0u;
    }
    __syncthreads();
#pragma unroll
    for (int k = 0; k < EPT; ++k) {
        int e = e0 + (k << 10) + tid;
        if (e < e1) {
            u32 b = dv[k] >> 9;
            u32 p = atomicAdd(&cur2[b], 1u);
            srec[p] = ((dv[k] & (NPB - 1u)) << 19) | sv[k];
            sbk[p] = (u16)b;
        }
    }
    __syncthreads();
    for (int p = tid; p < n; p += STB) {
        u32 b = sbk[p];
        u32 slot = gbase[b] + ((u32)p - scn_ex[b]);
        rec[(size_t)b * CAP + slot] = srec[p];
    }
}

// ---- per-bucket degree -> dis = rsqrt(deg+1) [f32], m1h = fp16(dis*x)
__global__ __launch_bounds__(LTB) void k_deg_dis(
        const u32* __restrict__ rec, const u32* __restrict__ cnt_g,
        const float* __restrict__ x,
        float* __restrict__ dis, u16* __restrict__ m1h) {
    __shared__ u32 cnt[NPB];
    int tid = threadIdx.x, bid = blockIdx.x;
    for (int l = tid; l < NPB; l += LTB) cnt[l] = 0;
    __syncthreads();
    const u32* r0 = rec + (size_t)bid * CAP;
    u32 n = cnt_g[bid];
    u32 nv = n >> 2;
    for (u32 i = tid; i < nv; i += LTB) {
        v4u r = stream4(r0 + ((size_t)i << 2));
        atomicAdd(&cnt[r.x >> 19], 1u);
        atomicAdd(&cnt[r.y >> 19], 1u);
        atomicAdd(&cnt[r.z >> 19], 1u);
        atomicAdd(&cnt[r.w >> 19], 1u);
    }
    for (u32 e = (nv << 2) + tid; e < n; e += LTB)
        atomicAdd(&cnt[nt1u(r0 + e) >> 19], 1u);
    __syncthreads();
    int node0 = bid << 9;
    int nn = min(NPB, N_NODES - node0);
    for (int l = tid; l < nn; l += LTB) {
        int node = node0 + l;
        float r = rsqrtf((float)(cnt[l] + 1u));   // +1 self-loop; always > 0
        dis[node] = r;
        m1h[node] = sth(r * x[node]);
    }
}

// ---- layer-1: gather fp16 m1h[src] + LDS f32 acc; per-node MLP -> h2mh, out
__global__ __launch_bounds__(LTB) void k_layer1(
        const u32* __restrict__ rec, const u32* __restrict__ cnt_g,
        const float* __restrict__ dis, const u16* __restrict__ m1h,
        const float* __restrict__ W1, const float* __restrict__ b1,
        const float* __restrict__ W2, const float* __restrict__ b2,
        u32* __restrict__ h2mh, float2* __restrict__ out) {
    __shared__ float acc[NPB];
    int tid = threadIdx.x, bid = blockIdx.x;
    for (int l = tid; l < NPB; l += LTB) acc[l] = 0.f;
    __syncthreads();
    const u32* r0 = rec + (size_t)bid * CAP;
    u32 n = cnt_g[bid];
    u32 nv = n >> 2;
    for (u32 i = tid; i < nv; i += LTB) {
        v4u r = stream4(r0 + ((size_t)i << 2));
        float v0 = ldh(m1h + (r.x & SRC19));
        float v1 = ldh(m1h + (r.y & SRC19));
        float v2 = ldh(m1h + (r.z & SRC19));
        float v3 = ldh(m1h + (r.w & SRC19));
        atomicAdd(&acc[r.x >> 19], v0);
        atomicAdd(&acc[r.y >> 19], v1);
        atomicAdd(&acc[r.z >> 19], v2);
        atomicAdd(&acc[r.w >> 19], v3);
    }
    for (u32 e = (nv << 2) + tid; e < n; e += LTB) {
        u32 r = nt1u(r0 + e);
        atomicAdd(&acc[r >> 19], ldh(m1h + (r & SRC19)));
    }
    __syncthreads();
    int node0 = bid << 9;
    int nn = min(NPB, N_NODES - node0);
    for (int l = tid; l < nn; l += LTB) {
        int node = node0 + l;
        float d = dis[node];
        float s = d * (acc[l] + ldh(m1h + node));
        float a0 = 0.f, a1 = 0.f;
#pragma unroll
        for (int k = 0; k < 8; ++k) {
            float h = fmaxf(W1[k] * s + b1[k], 0.f);
            a0 += h * W2[2 * k + 0];
            a1 += h * W2[2 * k + 1];
        }
        h2mh[node] = pack2h(d * a0, d * a1);                 // fp16 dis[src]*h2
        out[node] = make_float2(b2[0] + d * d * a0, b2[1] + d * d * a1);  // f32 self
    }
}

// ---- layer-2: gather packed half2 h2mh[src] + two LDS planes; out += dis*sum
__global__ __launch_bounds__(LTB) void k_layer2(
        const u32* __restrict__ rec, const u32* __restrict__ cnt_g,
        const float* __restrict__ dis, const u32* __restrict__ h2mh,
        float2* __restrict__ out) {
    __shared__ float ax[NPB];
    __shared__ float ay[NPB];
    int tid = threadIdx.x, bid = blockIdx.x;
    for (int l = tid; l < NPB; l += LTB) { ax[l] = 0.f; ay[l] = 0.f; }
    __syncthreads();
    const u32* r0 = rec + (size_t)bid * CAP;
    u32 n = cnt_g[bid];
    u32 nv = n >> 2;
    for (u32 i = tid; i < nv; i += LTB) {
        v4u r = stream4(r0 + ((size_t)i << 2));
        float2 v0 = unpack2h(h2mh[r.x & SRC19]);
        float2 v1 = unpack2h(h2mh[r.y & SRC19]);
        float2 v2 = unpack2h(h2mh[r.z & SRC19]);
        float2 v3 = unpack2h(h2mh[r.w & SRC19]);
        atomicAdd(&ax[r.x >> 19], v0.x);
        atomicAdd(&ay[r.x >> 19], v0.y);
        atomicAdd(&ax[r.y >> 19], v1.x);
        atomicAdd(&ay[r.y >> 19], v1.y);
        atomicAdd(&ax[r.z >> 19], v2.x);
        atomicAdd(&ay[r.z >> 19], v2.y);
        atomicAdd(&ax[r.w >> 19], v3.x);
        atomicAdd(&ay[r.w >> 19], v3.y);
    }
    for (u32 e = (nv << 2) + tid; e < n; e += LTB) {
        u32 r = nt1u(r0 + e);
        float2 v = unpack2h(h2mh[r & SRC19]);
        atomicAdd(&ax[r >> 19], v.x);
        atomicAdd(&ay[r >> 19], v.y);
    }
    __syncthreads();
    int node0 = bid << 9;
    int nn = min(NPB, N_NODES - node0);
    for (int l = tid; l < nn; l += LTB) {
        int node = node0 + l;
        float d = dis[node];
        float2 o = out[node];
        out[node] = make_float2(o.x + d * ax[l], o.y + d * ay[l]);
    }
}

// ===========================================================================
// Fallback path (R1): global atomics — only if ws too small (needs 10 MB).
// ===========================================================================
__global__ void f_count_deg(const int* __restrict__ dst, int E,
                            u32* __restrict__ deg) {
    int i = blockIdx.x * blockDim.x + threadIdx.x;
    int stride = gridDim.x * blockDim.x;
    for (int e = i; e < E; e += stride) atomicAdd(&deg[dst[e]], 1u);
}
__global__ void f_dis_sinit(const u32* __restrict__ deg, const float* __restrict__ x,
                            float* __restrict__ dis, float* __restrict__ s, int N) {
    int i = blockIdx.x * blockDim.x + threadIdx.x;
    if (i < N) {
        float r = rsqrtf((float)(deg[i] + 1u));
        dis[i] = r;
        s[i] = r * r * x[i];
    }
}
__global__ void f_agg1(const int* __restrict__ src, const int* __restrict__ dst,
                       int E, const float* __restrict__ dis,
                       const float* __restrict__ x, float* __restrict__ s) {
    int i = blockIdx.x * blockDim.x + threadIdx.x;
    int stride = gridDim.x * blockDim.x;
    for (int e = i; e < E; e += stride) {
        int sj = src[e], dj = dst[e];
        atomicAdd(&s[dj], dis[sj] * dis[dj] * x[sj]);
    }
}
__global__ void f_node2(const float* __restrict__ s, const float* __restrict__ dis,
                        const float* __restrict__ W1, const float* __restrict__ b1,
                        const float* __restrict__ W2, const float* __restrict__ b2,
                        float2* __restrict__ h2, float2* __restrict__ out, int N) {
    int i = blockIdx.x * blockDim.x + threadIdx.x;
    if (i >= N) return;
    float si = s[i];
    float a0 = 0.f, a1 = 0.f;
#pragma unroll
    for (int k = 0; k < 8; ++k) {
        float hk = fmaxf(W1[k] * si + b1[k], 0.f);
        a0 += hk * W2[2 * k + 0];
        a1 += hk * W2[2 * k + 1];
    }
    h2[i] = make_float2(a0, a1);
    float r2 = dis[i] * dis[i];
    out[i] = make_float2(b2[0] + r2 * a0, b2[1] + r2 * a1);
}
__global__ void f_agg2(const int* __restrict__ src, const int* __restrict__ dst,
                       int E, const float* __restrict__ dis,
                       const float2* __restrict__ h2, float* __restrict__ out) {
    int i = blockIdx.x * blockDim.x + threadIdx.x;
    int stride = gridDim.x * blockDim.x;
    for (int e = i; e < E; e += stride) {
        int sj = src[e], dj = dst[e];
        float nm = dis[sj] * dis[dj];
        float2 v = h2[sj];
        atomicAdd(&out[2 * dj + 0], nm * v.x);
        atomicAdd(&out[2 * dj + 1], nm * v.y);
    }
}

// ===========================================================================
extern "C" void kernel_launch(void* const* d_in, const int* in_sizes, int n_in,
                              void* d_out, int out_size, void* d_ws, size_t ws_size,
                              hipStream_t stream) {
    const float* x  = (const float*)d_in[0];
    const int*   ei = (const int*)d_in[1];   // [2,E]: src row, then dst row
    const float* W1 = (const float*)d_in[2];
    const float* b1 = (const float*)d_in[3];
    const float* W2 = (const float*)d_in[4];
    const float* b2 = (const float*)d_in[5];

    const int N = N_NODES;
    const int E = in_sizes[1] / 2;
    const int* src = ei;
    const int* dst = ei + E;
    float* out = (float*)d_out;
    char* ws = (char*)d_ws;

    // ---- fast-path workspace: cur | dis | m1h | h2mh | rec  (~85 MB) ----
    size_t off = 0;
    auto take = [&](size_t bytes) { size_t o = off; off = (off + bytes + 255) & ~(size_t)255; return o; };
    size_t off_cur  = take(NBUCK * 4);
    size_t off_dis  = take((size_t)N * 4);
    size_t off_m1h  = take((size_t)N * 2);
    size_t off_h2mh = take((size_t)N * 4);
    size_t off_rec  = take((size_t)NBUCK * CAP * 4 + 16);   // ~80 MB
    size_t need     = off;

    if (ws_size >= need) {
        u32* cur_g  = (u32*)(ws + off_cur);
        float* dis  = (float*)(ws + off_dis);
        u16* m1h    = (u16*)(ws + off_m1h);
        u32* h2mh   = (u32*)(ws + off_h2mh);
        u32* rec    = (u32*)(ws + off_rec);

        hipMemsetAsync(cur_g, 0, NBUCK * 4, stream);
        const int nchunks = (E + CH - 1) / CH;
        k_scatter_fused<<<nchunks, STB, 0, stream>>>(src, dst, E, cur_g, rec);
        k_deg_dis      <<<NBUCK,   LTB, 0, stream>>>(rec, cur_g, x, dis, m1h);
        k_layer1       <<<NBUCK,   LTB, 0, stream>>>(rec, cur_g, dis, m1h,
                                                     W1, b1, W2, b2,
                                                     h2mh, (float2*)out);
        k_layer2       <<<NBUCK,   LTB, 0, stream>>>(rec, cur_g, dis, h2mh,
                                                     (float2*)out);
        return;
    }

    // ---- fallback: R1 global-atomic path (10 MB ws) ----
    u32* deg    = (u32*)(ws);
    float* dis  = (float*)(ws + (size_t)N * 4);
    float* s    = (float*)(ws + (size_t)N * 8);
    float2* h2  = (float2*)(ws + (size_t)N * 12);
    hipMemsetAsync(deg, 0, (size_t)N * 4, stream);
    int nodeBlocks = (N + 255) / 256;
    int edgeBlocks = (E + 255) / 256;
    f_count_deg<<<edgeBlocks, 256, 0, stream>>>(dst, E, deg);
    f_dis_sinit<<<nodeBlocks, 256, 0, stream>>>(deg, x, dis, s, N);
    f_agg1     <<<edgeBlocks, 256, 0, stream>>>(src, dst, E, dis, x, s);
    f_node2    <<<nodeBlocks, 256, 0, stream>>>(s, dis, W1, b1, W2, b2, h2,
                                                (float2*)out, N);
    f_agg2     <<<edgeBlocks, 256, 0, stream>>>(src, dst, E, dis, h2, out);
}

// Round 9
// 466.395 us; speedup vs baseline: 1.1123x; 1.1123x over previous
//
#include <hip/hip_runtime.h>
#include <hip/hip_fp16.h>

#define N_NODES 500000
typedef unsigned int u32;
typedef unsigned short u16;
typedef unsigned long long u64;

// ===========================================================================
// R18: two-arm probe on the 6.4 cyc/edge layer wall.
//  Arm A (k_layer2): ONE packed u64 fixed-point LDS atomic per edge
//    (was 2 f32 atomics) -> tests LDS-atomic-serialization hypothesis.
//    enc = (int)rn(v*2^19) + 2^24 per component; carry-free since every
//    addend is positive and sums stay < 2^32; recovery subtracts deg*B
//    (deg16 exported by the deg pass).
//  Arm B (k_layer1): gathers via __builtin_nontemporal_load (no L1 alloc)
//    -> tests L1-miss-fill/replay-throughput hypothesis.
// Base = R16 (fp16 gather arrays, plain nt stream loads; R17 sc1 was null).
//   rec = dl9<<19 | src19   per 512-node dst bucket.
// ===========================================================================
#define NPB    512
#define NBUCK  ((N_NODES + NPB - 1) / NPB)   // 977
#define CAP    20480          // region capacity; E[fill]=16384, sigma~128 (32σ)
#define CH     8192           // edges per scatter chunk/WG
#define EPT    8              // edges per thread in scatter (CH / 1024)
#define STB    1024           // scatter block
#define LTB    512            // layer/deg block
#define SRC19  0x7FFFFu

#define FXS    524288.0f          // 2^19
#define FXSI   1.9073486328e-6f   // 2^-19
#define FXB    16777216u          // 2^24

typedef unsigned int v4u __attribute__((ext_vector_type(4)));
__device__ inline int  nt1i(const int* p) { return __builtin_nontemporal_load(p); }
__device__ inline u32  nt1u(const u32* p) { return __builtin_nontemporal_load(p); }
__device__ inline v4u  nt4u(const u32* p) { return __builtin_nontemporal_load((const v4u*)p); }

// fp16 helpers (storage = u16 / u32-packed half2; math in f32)
__device__ inline float ldh(const u16* p) {
    __half h = *(const __half*)p;
    return __half2float(h);
}
__device__ inline float ldhnt(const u16* p) {   // Arm B: no L1 allocate
    u16 raw = __builtin_nontemporal_load(p);
    __half h = *(__half*)&raw;
    return __half2float(h);
}
__device__ inline u16 sth(float v) {
    __half h = __float2half(v);
    return *(u16*)&h;
}
__device__ inline u32 pack2h(float a, float b) {
    union { __half2 h; u32 u; } cvt;
    cvt.h = __floats2half2_rn(a, b);
    return cvt.u;
}
__device__ inline float2 unpack2h(u32 w) {
    union { u32 u; __half2 h; } cvt;
    cvt.u = w;
    return __half22float2(cvt.h);
}
// Arm A: bias-encoded fixed-point pack of a float2 into u64 (two u32 lanes)
__device__ inline u64 packfx(float2 v) {
    u32 ex = (u32)__float2int_rn(v.x * FXS) + FXB;
    u32 ey = (u32)__float2int_rn(v.y * FXS) + FXB;
    return ((u64)ey << 32) | (u64)ex;
}

// ---- fused scatter: edges register-cached; LDS histogram + scan + presort;
//      coalesced run writes into fixed bucket regions.  (R9 verbatim)
__global__ __launch_bounds__(STB) void k_scatter_fused(
        const int* __restrict__ src, const int* __restrict__ dst, int E,
        u32* __restrict__ cur_g, u32* __restrict__ rec) {
    __shared__ u32 srec[CH];        // 32 KB
    __shared__ u16 sbk[CH];         // 16 KB
    __shared__ u32 hist[NBUCK];     // 3.9 KB
    __shared__ u32 sc[1024];        // 4 KB
    __shared__ u32 scn_ex[NBUCK];
    __shared__ u32 cur2[NBUCK];
    __shared__ u32 gbase[NBUCK];
    int tid = threadIdx.x, bid = blockIdx.x;
    for (int b = tid; b < NBUCK; b += STB) hist[b] = 0;
    __syncthreads();
    int e0 = bid * CH, e1 = min(E, e0 + CH), n = e1 - e0;
    u32 dv[EPT], sv[EPT];
#pragma unroll
    for (int k = 0; k < EPT; ++k) {
        int e = e0 + (k << 10) + tid;
        if (e < e1) {
            dv[k] = (u32)nt1i(dst + e);
            sv[k] = (u32)nt1i(src + e);
            atomicAdd(&hist[dv[k] >> 9], 1u);
        }
    }
    __syncthreads();
    sc[tid] = (tid < NBUCK) ? hist[tid] : 0u;
    __syncthreads();
    for (int off = 1; off < 1024; off <<= 1) {
        u32 t = (tid >= off) ? sc[tid - off] : 0u;
        __syncthreads();
        sc[tid] += t;
        __syncthreads();
    }
    if (tid < NBUCK) {
        u32 ex = sc[tid] - hist[tid];
        scn_ex[tid] = ex;
        cur2[tid] = ex;
        gbase[tid] = hist[tid] ? atomicAdd(&cur_g[tid], hist[tid]) : 0u;
    }
    __syncthreads();
#pragma unroll
    for (int k = 0; k < EPT; ++k) {
        int e = e0 + (k << 10) + tid;
        if (e < e1) {
            u32 b = dv[k] >> 9;
            u32 p = atomicAdd(&cur2[b], 1u);
            srec[p] = ((dv[k] & (NPB - 1u)) << 19) | sv[k];
            sbk[p] = (u16)b;
        }
    }
    __syncthreads();
    for (int p = tid; p < n; p += STB) {
        u32 b = sbk[p];
        u32 slot = gbase[b] + ((u32)p - scn_ex[b]);
        rec[(size_t)b * CAP + slot] = srec[p];
    }
}

// ---- per-bucket degree -> dis = rsqrt(deg+1) [f32], m1h = fp16(dis*x),
//      deg16 exported for the layer-2 fixed-point bias recovery.
__global__ __launch_bounds__(LTB) void k_deg_dis(
        const u32* __restrict__ rec, const u32* __restrict__ cnt_g,
        const float* __restrict__ x,
        float* __restrict__ dis, u16* __restrict__ m1h,
        u16* __restrict__ deg16) {
    __shared__ u32 cnt[NPB];
    int tid = threadIdx.x, bid = blockIdx.x;
    for (int l = tid; l < NPB; l += LTB) cnt[l] = 0;
    __syncthreads();
    const u32* r0 = rec + (size_t)bid * CAP;
    u32 n = cnt_g[bid];
    u32 nv = n >> 2;
    for (u32 i = tid; i < nv; i += LTB) {
        v4u r = nt4u(r0 + ((size_t)i << 2));
        atomicAdd(&cnt[r.x >> 19], 1u);
        atomicAdd(&cnt[r.y >> 19], 1u);
        atomicAdd(&cnt[r.z >> 19], 1u);
        atomicAdd(&cnt[r.w >> 19], 1u);
    }
    for (u32 e = (nv << 2) + tid; e < n; e += LTB)
        atomicAdd(&cnt[nt1u(r0 + e) >> 19], 1u);
    __syncthreads();
    int node0 = bid << 9;
    int nn = min(NPB, N_NODES - node0);
    for (int l = tid; l < nn; l += LTB) {
        int node = node0 + l;
        u32 c = cnt[l];
        float r = rsqrtf((float)(c + 1u));   // +1 self-loop; always > 0
        dis[node] = r;
        m1h[node] = sth(r * x[node]);
        deg16[node] = (u16)c;
    }
}

// ---- layer-1 (Arm B): nt gathers of fp16 m1h[src] + LDS f32 acc; MLP
__global__ __launch_bounds__(LTB) void k_layer1(
        const u32* __restrict__ rec, const u32* __restrict__ cnt_g,
        const float* __restrict__ dis, const u16* __restrict__ m1h,
        const float* __restrict__ W1, const float* __restrict__ b1,
        const float* __restrict__ W2, const float* __restrict__ b2,
        u32* __restrict__ h2mh, float2* __restrict__ out) {
    __shared__ float acc[NPB];
    int tid = threadIdx.x, bid = blockIdx.x;
    for (int l = tid; l < NPB; l += LTB) acc[l] = 0.f;
    __syncthreads();
    const u32* r0 = rec + (size_t)bid * CAP;
    u32 n = cnt_g[bid];
    u32 nv = n >> 2;
    for (u32 i = tid; i < nv; i += LTB) {
        v4u r = nt4u(r0 + ((size_t)i << 2));
        float v0 = ldhnt(m1h + (r.x & SRC19));
        float v1 = ldhnt(m1h + (r.y & SRC19));
        float v2 = ldhnt(m1h + (r.z & SRC19));
        float v3 = ldhnt(m1h + (r.w & SRC19));
        atomicAdd(&acc[r.x >> 19], v0);
        atomicAdd(&acc[r.y >> 19], v1);
        atomicAdd(&acc[r.z >> 19], v2);
        atomicAdd(&acc[r.w >> 19], v3);
    }
    for (u32 e = (nv << 2) + tid; e < n; e += LTB) {
        u32 r = nt1u(r0 + e);
        atomicAdd(&acc[r >> 19], ldhnt(m1h + (r & SRC19)));
    }
    __syncthreads();
    int node0 = bid << 9;
    int nn = min(NPB, N_NODES - node0);
    for (int l = tid; l < nn; l += LTB) {
        int node = node0 + l;
        float d = dis[node];
        float s = d * (acc[l] + ldh(m1h + node));
        float a0 = 0.f, a1 = 0.f;
#pragma unroll
        for (int k = 0; k < 8; ++k) {
            float h = fmaxf(W1[k] * s + b1[k], 0.f);
            a0 += h * W2[2 * k + 0];
            a1 += h * W2[2 * k + 1];
        }
        h2mh[node] = pack2h(d * a0, d * a1);                 // fp16 dis[src]*h2
        out[node] = make_float2(b2[0] + d * d * a0, b2[1] + d * d * a1);  // f32 self
    }
}

// ---- layer-2 (Arm A): gather half2 h2mh[src]; ONE packed u64 LDS atomic
//      per edge; node pass recovers via deg16 bias subtraction.
__global__ __launch_bounds__(LTB) void k_layer2(
        const u32* __restrict__ rec, const u32* __restrict__ cnt_g,
        const float* __restrict__ dis, const u32* __restrict__ h2mh,
        const u16* __restrict__ deg16, float2* __restrict__ out) {
    __shared__ u64 sacc[NPB];       // 4 KB (same as the old two f32 planes)
    int tid = threadIdx.x, bid = blockIdx.x;
    for (int l = tid; l < NPB; l += LTB) sacc[l] = 0ull;
    __syncthreads();
    const u32* r0 = rec + (size_t)bid * CAP;
    u32 n = cnt_g[bid];
    u32 nv = n >> 2;
    for (u32 i = tid; i < nv; i += LTB) {
        v4u r = nt4u(r0 + ((size_t)i << 2));
        float2 v0 = unpack2h(h2mh[r.x & SRC19]);
        float2 v1 = unpack2h(h2mh[r.y & SRC19]);
        float2 v2 = unpack2h(h2mh[r.z & SRC19]);
        float2 v3 = unpack2h(h2mh[r.w & SRC19]);
        atomicAdd(&sacc[r.x >> 19], packfx(v0));
        atomicAdd(&sacc[r.y >> 19], packfx(v1));
        atomicAdd(&sacc[r.z >> 19], packfx(v2));
        atomicAdd(&sacc[r.w >> 19], packfx(v3));
    }
    for (u32 e = (nv << 2) + tid; e < n; e += LTB) {
        u32 r = nt1u(r0 + e);
        float2 v = unpack2h(h2mh[r & SRC19]);
        atomicAdd(&sacc[r >> 19], packfx(v));
    }
    __syncthreads();
    int node0 = bid << 9;
    int nn = min(NPB, N_NODES - node0);
    for (int l = tid; l < nn; l += LTB) {
        int node = node0 + l;
        u64 a = sacc[l];
        u32 dgB = (u32)deg16[node] * FXB;
        float sx = (float)(int)((u32)a - dgB) * FXSI;
        float sy = (float)(int)((u32)(a >> 32) - dgB) * FXSI;
        float d = dis[node];
        float2 o = out[node];
        out[node] = make_float2(o.x + d * sx, o.y + d * sy);
    }
}

// ===========================================================================
// Fallback path (R1): global atomics — only if ws too small (needs 10 MB).
// ===========================================================================
__global__ void f_count_deg(const int* __restrict__ dst, int E,
                            u32* __restrict__ deg) {
    int i = blockIdx.x * blockDim.x + threadIdx.x;
    int stride = gridDim.x * blockDim.x;
    for (int e = i; e < E; e += stride) atomicAdd(&deg[dst[e]], 1u);
}
__global__ void f_dis_sinit(const u32* __restrict__ deg, const float* __restrict__ x,
                            float* __restrict__ dis, float* __restrict__ s, int N) {
    int i = blockIdx.x * blockDim.x + threadIdx.x;
    if (i < N) {
        float r = rsqrtf((float)(deg[i] + 1u));
        dis[i] = r;
        s[i] = r * r * x[i];
    }
}
__global__ void f_agg1(const int* __restrict__ src, const int* __restrict__ dst,
                       int E, const float* __restrict__ dis,
                       const float* __restrict__ x, float* __restrict__ s) {
    int i = blockIdx.x * blockDim.x + threadIdx.x;
    int stride = gridDim.x * blockDim.x;
    for (int e = i; e < E; e += stride) {
        int sj = src[e], dj = dst[e];
        atomicAdd(&s[dj], dis[sj] * dis[dj] * x[sj]);
    }
}
__global__ void f_node2(const float* __restrict__ s, const float* __restrict__ dis,
                        const float* __restrict__ W1, const float* __restrict__ b1,
                        const float* __restrict__ W2, const float* __restrict__ b2,
                        float2* __restrict__ h2, float2* __restrict__ out, int N) {
    int i = blockIdx.x * blockDim.x + threadIdx.x;
    if (i >= N) return;
    float si = s[i];
    float a0 = 0.f, a1 = 0.f;
#pragma unroll
    for (int k = 0; k < 8; ++k) {
        float hk = fmaxf(W1[k] * si + b1[k], 0.f);
        a0 += hk * W2[2 * k + 0];
        a1 += hk * W2[2 * k + 1];
    }
    h2[i] = make_float2(a0, a1);
    float r2 = dis[i] * dis[i];
    out[i] = make_float2(b2[0] + r2 * a0, b2[1] + r2 * a1);
}
__global__ void f_agg2(const int* __restrict__ src, const int* __restrict__ dst,
                       int E, const float* __restrict__ dis,
                       const float2* __restrict__ h2, float* __restrict__ out) {
    int i = blockIdx.x * blockDim.x + threadIdx.x;
    int stride = gridDim.x * blockDim.x;
    for (int e = i; e < E; e += stride) {
        int sj = src[e], dj = dst[e];
        float nm = dis[sj] * dis[dj];
        float2 v = h2[sj];
        atomicAdd(&out[2 * dj + 0], nm * v.x);
        atomicAdd(&out[2 * dj + 1], nm * v.y);
    }
}

// ===========================================================================
extern "C" void kernel_launch(void* const* d_in, const int* in_sizes, int n_in,
                              void* d_out, int out_size, void* d_ws, size_t ws_size,
                              hipStream_t stream) {
    const float* x  = (const float*)d_in[0];
    const int*   ei = (const int*)d_in[1];   // [2,E]: src row, then dst row
    const float* W1 = (const float*)d_in[2];
    const float* b1 = (const float*)d_in[3];
    const float* W2 = (const float*)d_in[4];
    const float* b2 = (const float*)d_in[5];

    const int N = N_NODES;
    const int E = in_sizes[1] / 2;
    const int* src = ei;
    const int* dst = ei + E;
    float* out = (float*)d_out;
    char* ws = (char*)d_ws;

    // ---- fast-path workspace: cur | dis | m1h | h2mh | deg16 | rec (~86 MB) ----
    size_t off = 0;
    auto take = [&](size_t bytes) { size_t o = off; off = (off + bytes + 255) & ~(size_t)255; return o; };
    size_t off_cur  = take(NBUCK * 4);
    size_t off_dis  = take((size_t)N * 4);
    size_t off_m1h  = take((size_t)N * 2);
    size_t off_h2mh = take((size_t)N * 4);
    size_t off_dg   = take((size_t)N * 2);
    size_t off_rec  = take((size_t)NBUCK * CAP * 4 + 16);   // ~80 MB
    size_t need     = off;

    if (ws_size >= need) {
        u32* cur_g  = (u32*)(ws + off_cur);
        float* dis  = (float*)(ws + off_dis);
        u16* m1h    = (u16*)(ws + off_m1h);
        u32* h2mh   = (u32*)(ws + off_h2mh);
        u16* deg16  = (u16*)(ws + off_dg);
        u32* rec    = (u32*)(ws + off_rec);

        hipMemsetAsync(cur_g, 0, NBUCK * 4, stream);
        const int nchunks = (E + CH - 1) / CH;
        k_scatter_fused<<<nchunks, STB, 0, stream>>>(src, dst, E, cur_g, rec);
        k_deg_dis      <<<NBUCK,   LTB, 0, stream>>>(rec, cur_g, x, dis, m1h,
                                                     deg16);
        k_layer1       <<<NBUCK,   LTB, 0, stream>>>(rec, cur_g, dis, m1h,
                                                     W1, b1, W2, b2,
                                                     h2mh, (float2*)out);
        k_layer2       <<<NBUCK,   LTB, 0, stream>>>(rec, cur_g, dis, h2mh,
                                                     deg16, (float2*)out);
        return;
    }

    // ---- fallback: R1 global-atomic path (10 MB ws) ----
    u32* deg    = (u32*)(ws);
    float* dis  = (float*)(ws + (size_t)N * 4);
    float* s    = (float*)(ws + (size_t)N * 8);
    float2* h2  = (float2*)(ws + (size_t)N * 12);
    hipMemsetAsync(deg, 0, (size_t)N * 4, stream);
    int nodeBlocks = (N + 255) / 256;
    int edgeBlocks = (E + 255) / 256;
    f_count_deg<<<edgeBlocks, 256, 0, stream>>>(dst, E, deg);
    f_dis_sinit<<<nodeBlocks, 256, 0, stream>>>(deg, x, dis, s, N);
    f_agg1     <<<edgeBlocks, 256, 0, stream>>>(src, dst, E, dis, x, s);
    f_node2    <<<nodeBlocks, 256, 0, stream>>>(s, dis, W1, b1, W2, b2, h2,
                                                (float2*)out, N);
    f_agg2     <<<edgeBlocks, 256, 0, stream>>>(src, dst, E, dis, h2, out);
}

// Round 10
// 463.866 us; speedup vs baseline: 1.1183x; 1.0055x over previous
//
#include <hip/hip_runtime.h>
#include <hip/hip_fp16.h>

#define N_NODES 500000
typedef unsigned int u32;
typedef unsigned short u16;
typedef unsigned long long u64;

// ===========================================================================
// R19 = R18 + layer1 f32-LDS-atomic -> u32 fixed-point int atomic.
// R18 result: l2's 2xf32->1xu64-int atomic merge dropped it 177 -> <105us
// (total 516->466). The five-round invariance series is explained: the wall
// is LDS-atomic issue cost, which no prior round changed. l1 (now slowest,
// 106us) still uses ds_add_f32. Convert to the proven bias-encoded int
// scheme: enc = rn(v*2^19)+2^24, one u32 atomic/edge, recover via deg16.
// Overflow-safe (max deg ~61 -> sum < 1.3e9 << 2^32); quant ~3e-5.
//   rec = dl9<<19 | src19   per 512-node dst bucket.
// ===========================================================================
#define NPB    512
#define NBUCK  ((N_NODES + NPB - 1) / NPB)   // 977
#define CAP    20480          // region capacity; E[fill]=16384, sigma~128 (32σ)
#define CH     8192           // edges per scatter chunk/WG
#define EPT    8              // edges per thread in scatter (CH / 1024)
#define STB    1024           // scatter block
#define LTB    512            // layer/deg block
#define SRC19  0x7FFFFu

#define FXS    524288.0f          // 2^19
#define FXSI   1.9073486328e-6f   // 2^-19
#define FXB    16777216u          // 2^24

typedef unsigned int v4u __attribute__((ext_vector_type(4)));
__device__ inline int  nt1i(const int* p) { return __builtin_nontemporal_load(p); }
__device__ inline u32  nt1u(const u32* p) { return __builtin_nontemporal_load(p); }
__device__ inline v4u  nt4u(const u32* p) { return __builtin_nontemporal_load((const v4u*)p); }

// fp16 helpers (storage = u16 / u32-packed half2; math in f32)
__device__ inline float ldh(const u16* p) {
    __half h = *(const __half*)p;
    return __half2float(h);
}
__device__ inline float ldhnt(const u16* p) {   // no L1 allocate
    u16 raw = __builtin_nontemporal_load(p);
    __half h = *(__half*)&raw;
    return __half2float(h);
}
__device__ inline u16 sth(float v) {
    __half h = __float2half(v);
    return *(u16*)&h;
}
__device__ inline u32 pack2h(float a, float b) {
    union { __half2 h; u32 u; } cvt;
    cvt.h = __floats2half2_rn(a, b);
    return cvt.u;
}
__device__ inline float2 unpack2h(u32 w) {
    union { u32 u; __half2 h; } cvt;
    cvt.u = w;
    return __half22float2(cvt.h);
}
// bias-encoded fixed-point: scalar (layer1) and float2->u64 (layer2)
__device__ inline u32 packfx1(float v) {
    return (u32)__float2int_rn(v * FXS) + FXB;
}
__device__ inline u64 packfx(float2 v) {
    u32 ex = (u32)__float2int_rn(v.x * FXS) + FXB;
    u32 ey = (u32)__float2int_rn(v.y * FXS) + FXB;
    return ((u64)ey << 32) | (u64)ex;
}

// ---- fused scatter: edges register-cached; LDS histogram + scan + presort;
//      coalesced run writes into fixed bucket regions.  (R9 verbatim)
__global__ __launch_bounds__(STB) void k_scatter_fused(
        const int* __restrict__ src, const int* __restrict__ dst, int E,
        u32* __restrict__ cur_g, u32* __restrict__ rec) {
    __shared__ u32 srec[CH];        // 32 KB
    __shared__ u16 sbk[CH];         // 16 KB
    __shared__ u32 hist[NBUCK];     // 3.9 KB
    __shared__ u32 sc[1024];        // 4 KB
    __shared__ u32 scn_ex[NBUCK];
    __shared__ u32 cur2[NBUCK];
    __shared__ u32 gbase[NBUCK];
    int tid = threadIdx.x, bid = blockIdx.x;
    for (int b = tid; b < NBUCK; b += STB) hist[b] = 0;
    __syncthreads();
    int e0 = bid * CH, e1 = min(E, e0 + CH), n = e1 - e0;
    u32 dv[EPT], sv[EPT];
#pragma unroll
    for (int k = 0; k < EPT; ++k) {
        int e = e0 + (k << 10) + tid;
        if (e < e1) {
            dv[k] = (u32)nt1i(dst + e);
            sv[k] = (u32)nt1i(src + e);
            atomicAdd(&hist[dv[k] >> 9], 1u);
        }
    }
    __syncthreads();
    sc[tid] = (tid < NBUCK) ? hist[tid] : 0u;
    __syncthreads();
    for (int off = 1; off < 1024; off <<= 1) {
        u32 t = (tid >= off) ? sc[tid - off] : 0u;
        __syncthreads();
        sc[tid] += t;
        __syncthreads();
    }
    if (tid < NBUCK) {
        u32 ex = sc[tid] - hist[tid];
        scn_ex[tid] = ex;
        cur2[tid] = ex;
        gbase[tid] = hist[tid] ? atomicAdd(&cur_g[tid], hist[tid]) : 0u;
    }
    __syncthreads();
#pragma unroll
    for (int k = 0; k < EPT; ++k) {
        int e = e0 + (k << 10) + tid;
        if (e < e1) {
            u32 b = dv[k] >> 9;
            u32 p = atomicAdd(&cur2[b], 1u);
            srec[p] = ((dv[k] & (NPB - 1u)) << 19) | sv[k];
            sbk[p] = (u16)b;
        }
    }
    __syncthreads();
    for (int p = tid; p < n; p += STB) {
        u32 b = sbk[p];
        u32 slot = gbase[b] + ((u32)p - scn_ex[b]);
        rec[(size_t)b * CAP + slot] = srec[p];
    }
}

// ---- per-bucket degree -> dis = rsqrt(deg+1) [f32], m1h = fp16(dis*x),
//      deg16 exported for fixed-point bias recovery in both layers.
__global__ __launch_bounds__(LTB) void k_deg_dis(
        const u32* __restrict__ rec, const u32* __restrict__ cnt_g,
        const float* __restrict__ x,
        float* __restrict__ dis, u16* __restrict__ m1h,
        u16* __restrict__ deg16) {
    __shared__ u32 cnt[NPB];
    int tid = threadIdx.x, bid = blockIdx.x;
    for (int l = tid; l < NPB; l += LTB) cnt[l] = 0;
    __syncthreads();
    const u32* r0 = rec + (size_t)bid * CAP;
    u32 n = cnt_g[bid];
    u32 nv = n >> 2;
    for (u32 i = tid; i < nv; i += LTB) {
        v4u r = nt4u(r0 + ((size_t)i << 2));
        atomicAdd(&cnt[r.x >> 19], 1u);
        atomicAdd(&cnt[r.y >> 19], 1u);
        atomicAdd(&cnt[r.z >> 19], 1u);
        atomicAdd(&cnt[r.w >> 19], 1u);
    }
    for (u32 e = (nv << 2) + tid; e < n; e += LTB)
        atomicAdd(&cnt[nt1u(r0 + e) >> 19], 1u);
    __syncthreads();
    int node0 = bid << 9;
    int nn = min(NPB, N_NODES - node0);
    for (int l = tid; l < nn; l += LTB) {
        int node = node0 + l;
        u32 c = cnt[l];
        float r = rsqrtf((float)(c + 1u));   // +1 self-loop; always > 0
        dis[node] = r;
        m1h[node] = sth(r * x[node]);
        deg16[node] = (u16)c;
    }
}

// ---- layer-1: nt gathers of fp16 m1h[src]; ONE u32 fixed-point LDS atomic
//      per edge; epilogue recovers via deg16 bias subtraction, runs MLP.
__global__ __launch_bounds__(LTB) void k_layer1(
        const u32* __restrict__ rec, const u32* __restrict__ cnt_g,
        const float* __restrict__ dis, const u16* __restrict__ m1h,
        const u16* __restrict__ deg16,
        const float* __restrict__ W1, const float* __restrict__ b1,
        const float* __restrict__ W2, const float* __restrict__ b2,
        u32* __restrict__ h2mh, float2* __restrict__ out) {
    __shared__ u32 sacc[NPB];       // 2 KB
    int tid = threadIdx.x, bid = blockIdx.x;
    for (int l = tid; l < NPB; l += LTB) sacc[l] = 0u;
    __syncthreads();
    const u32* r0 = rec + (size_t)bid * CAP;
    u32 n = cnt_g[bid];
    u32 nv = n >> 2;
    for (u32 i = tid; i < nv; i += LTB) {
        v4u r = nt4u(r0 + ((size_t)i << 2));
        float v0 = ldhnt(m1h + (r.x & SRC19));
        float v1 = ldhnt(m1h + (r.y & SRC19));
        float v2 = ldhnt(m1h + (r.z & SRC19));
        float v3 = ldhnt(m1h + (r.w & SRC19));
        atomicAdd(&sacc[r.x >> 19], packfx1(v0));
        atomicAdd(&sacc[r.y >> 19], packfx1(v1));
        atomicAdd(&sacc[r.z >> 19], packfx1(v2));
        atomicAdd(&sacc[r.w >> 19], packfx1(v3));
    }
    for (u32 e = (nv << 2) + tid; e < n; e += LTB) {
        u32 r = nt1u(r0 + e);
        atomicAdd(&sacc[r >> 19], packfx1(ldhnt(m1h + (r & SRC19))));
    }
    __syncthreads();
    int node0 = bid << 9;
    int nn = min(NPB, N_NODES - node0);
    for (int l = tid; l < nn; l += LTB) {
        int node = node0 + l;
        u32 dgB = (u32)deg16[node] * FXB;
        float accv = (float)(int)(sacc[l] - dgB) * FXSI;
        float d = dis[node];
        float s = d * (accv + ldh(m1h + node));
        float a0 = 0.f, a1 = 0.f;
#pragma unroll
        for (int k = 0; k < 8; ++k) {
            float h = fmaxf(W1[k] * s + b1[k], 0.f);
            a0 += h * W2[2 * k + 0];
            a1 += h * W2[2 * k + 1];
        }
        h2mh[node] = pack2h(d * a0, d * a1);                 // fp16 dis[src]*h2
        out[node] = make_float2(b2[0] + d * d * a0, b2[1] + d * d * a1);  // f32 self
    }
}

// ---- layer-2: gather half2 h2mh[src]; ONE packed u64 LDS atomic per edge;
//      node pass recovers via deg16 bias subtraction.  (R18 Arm A, proven)
__global__ __launch_bounds__(LTB) void k_layer2(
        const u32* __restrict__ rec, const u32* __restrict__ cnt_g,
        const float* __restrict__ dis, const u32* __restrict__ h2mh,
        const u16* __restrict__ deg16, float2* __restrict__ out) {
    __shared__ u64 sacc[NPB];       // 4 KB
    int tid = threadIdx.x, bid = blockIdx.x;
    for (int l = tid; l < NPB; l += LTB) sacc[l] = 0ull;
    __syncthreads();
    const u32* r0 = rec + (size_t)bid * CAP;
    u32 n = cnt_g[bid];
    u32 nv = n >> 2;
    for (u32 i = tid; i < nv; i += LTB) {
        v4u r = nt4u(r0 + ((size_t)i << 2));
        float2 v0 = unpack2h(h2mh[r.x & SRC19]);
        float2 v1 = unpack2h(h2mh[r.y & SRC19]);
        float2 v2 = unpack2h(h2mh[r.z & SRC19]);
        float2 v3 = unpack2h(h2mh[r.w & SRC19]);
        atomicAdd(&sacc[r.x >> 19], packfx(v0));
        atomicAdd(&sacc[r.y >> 19], packfx(v1));
        atomicAdd(&sacc[r.z >> 19], packfx(v2));
        atomicAdd(&sacc[r.w >> 19], packfx(v3));
    }
    for (u32 e = (nv << 2) + tid; e < n; e += LTB) {
        u32 r = nt1u(r0 + e);
        float2 v = unpack2h(h2mh[r & SRC19]);
        atomicAdd(&sacc[r >> 19], packfx(v));
    }
    __syncthreads();
    int node0 = bid << 9;
    int nn = min(NPB, N_NODES - node0);
    for (int l = tid; l < nn; l += LTB) {
        int node = node0 + l;
        u64 a = sacc[l];
        u32 dgB = (u32)deg16[node] * FXB;
        float sx = (float)(int)((u32)a - dgB) * FXSI;
        float sy = (float)(int)((u32)(a >> 32) - dgB) * FXSI;
        float d = dis[node];
        float2 o = out[node];
        out[node] = make_float2(o.x + d * sx, o.y + d * sy);
    }
}

// ===========================================================================
// Fallback path (R1): global atomics — only if ws too small (needs 10 MB).
// ===========================================================================
__global__ void f_count_deg(const int* __restrict__ dst, int E,
                            u32* __restrict__ deg) {
    int i = blockIdx.x * blockDim.x + threadIdx.x;
    int stride = gridDim.x * blockDim.x;
    for (int e = i; e < E; e += stride) atomicAdd(&deg[dst[e]], 1u);
}
__global__ void f_dis_sinit(const u32* __restrict__ deg, const float* __restrict__ x,
                            float* __restrict__ dis, float* __restrict__ s, int N) {
    int i = blockIdx.x * blockDim.x + threadIdx.x;
    if (i < N) {
        float r = rsqrtf((float)(deg[i] + 1u));
        dis[i] = r;
        s[i] = r * r * x[i];
    }
}
__global__ void f_agg1(const int* __restrict__ src, const int* __restrict__ dst,
                       int E, const float* __restrict__ dis,
                       const float* __restrict__ x, float* __restrict__ s) {
    int i = blockIdx.x * blockDim.x + threadIdx.x;
    int stride = gridDim.x * blockDim.x;
    for (int e = i; e < E; e += stride) {
        int sj = src[e], dj = dst[e];
        atomicAdd(&s[dj], dis[sj] * dis[dj] * x[sj]);
    }
}
__global__ void f_node2(const float* __restrict__ s, const float* __restrict__ dis,
                        const float* __restrict__ W1, const float* __restrict__ b1,
                        const float* __restrict__ W2, const float* __restrict__ b2,
                        float2* __restrict__ h2, float2* __restrict__ out, int N) {
    int i = blockIdx.x * blockDim.x + threadIdx.x;
    if (i >= N) return;
    float si = s[i];
    float a0 = 0.f, a1 = 0.f;
#pragma unroll
    for (int k = 0; k < 8; ++k) {
        float hk = fmaxf(W1[k] * si + b1[k], 0.f);
        a0 += hk * W2[2 * k + 0];
        a1 += hk * W2[2 * k + 1];
    }
    h2[i] = make_float2(a0, a1);
    float r2 = dis[i] * dis[i];
    out[i] = make_float2(b2[0] + r2 * a0, b2[1] + r2 * a1);
}
__global__ void f_agg2(const int* __restrict__ src, const int* __restrict__ dst,
                       int E, const float* __restrict__ dis,
                       const float2* __restrict__ h2, float* __restrict__ out) {
    int i = blockIdx.x * blockDim.x + threadIdx.x;
    int stride = gridDim.x * blockDim.x;
    for (int e = i; e < E; e += stride) {
        int sj = src[e], dj = dst[e];
        float nm = dis[sj] * dis[dj];
        float2 v = h2[sj];
        atomicAdd(&out[2 * dj + 0], nm * v.x);
        atomicAdd(&out[2 * dj + 1], nm * v.y);
    }
}

// ===========================================================================
extern "C" void kernel_launch(void* const* d_in, const int* in_sizes, int n_in,
                              void* d_out, int out_size, void* d_ws, size_t ws_size,
                              hipStream_t stream) {
    const float* x  = (const float*)d_in[0];
    const int*   ei = (const int*)d_in[1];   // [2,E]: src row, then dst row
    const float* W1 = (const float*)d_in[2];
    const float* b1 = (const float*)d_in[3];
    const float* W2 = (const float*)d_in[4];
    const float* b2 = (const float*)d_in[5];

    const int N = N_NODES;
    const int E = in_sizes[1] / 2;
    const int* src = ei;
    const int* dst = ei + E;
    float* out = (float*)d_out;
    char* ws = (char*)d_ws;

    // ---- fast-path workspace: cur | dis | m1h | h2mh | deg16 | rec (~86 MB) ----
    size_t off = 0;
    auto take = [&](size_t bytes) { size_t o = off; off = (off + bytes + 255) & ~(size_t)255; return o; };
    size_t off_cur  = take(NBUCK * 4);
    size_t off_dis  = take((size_t)N * 4);
    size_t off_m1h  = take((size_t)N * 2);
    size_t off_h2mh = take((size_t)N * 4);
    size_t off_dg   = take((size_t)N * 2);
    size_t off_rec  = take((size_t)NBUCK * CAP * 4 + 16);   // ~80 MB
    size_t need     = off;

    if (ws_size >= need) {
        u32* cur_g  = (u32*)(ws + off_cur);
        float* dis  = (float*)(ws + off_dis);
        u16* m1h    = (u16*)(ws + off_m1h);
        u32* h2mh   = (u32*)(ws + off_h2mh);
        u16* deg16  = (u16*)(ws + off_dg);
        u32* rec    = (u32*)(ws + off_rec);

        hipMemsetAsync(cur_g, 0, NBUCK * 4, stream);
        const int nchunks = (E + CH - 1) / CH;
        k_scatter_fused<<<nchunks, STB, 0, stream>>>(src, dst, E, cur_g, rec);
        k_deg_dis      <<<NBUCK,   LTB, 0, stream>>>(rec, cur_g, x, dis, m1h,
                                                     deg16);
        k_layer1       <<<NBUCK,   LTB, 0, stream>>>(rec, cur_g, dis, m1h,
                                                     deg16, W1, b1, W2, b2,
                                                     h2mh, (float2*)out);
        k_layer2       <<<NBUCK,   LTB, 0, stream>>>(rec, cur_g, dis, h2mh,
                                                     deg16, (float2*)out);
        return;
    }

    // ---- fallback: R1 global-atomic path (10 MB ws) ----
    u32* deg    = (u32*)(ws);
    float* dis  = (float*)(ws + (size_t)N * 4);
    float* s    = (float*)(ws + (size_t)N * 8);
    float2* h2  = (float2*)(ws + (size_t)N * 12);
    hipMemsetAsync(deg, 0, (size_t)N * 4, stream);
    int nodeBlocks = (N + 255) / 256;
    int edgeBlocks = (E + 255) / 256;
    f_count_deg<<<edgeBlocks, 256, 0, stream>>>(dst, E, deg);
    f_dis_sinit<<<nodeBlocks, 256, 0, stream>>>(deg, x, dis, s, N);
    f_agg1     <<<edgeBlocks, 256, 0, stream>>>(src, dst, E, dis, x, s);
    f_node2    <<<nodeBlocks, 256, 0, stream>>>(s, dis, W1, b1, W2, b2, h2,
                                                (float2*)out, N);
    f_agg2     <<<edgeBlocks, 256, 0, stream>>>(src, dst, E, dis, h2, out);
}